// Round 1
// baseline (148.787 us; speedup 1.0000x reference)
//
#include <hip/hip_runtime.h>
#include <hip/hip_bf16.h>

#define N_NODES 4096
#define F_DIM   512
#define U_DIM   64
#define H_HEADS 8
#define C_DIM   512   // H*U
#define LRELU_S 0.2f
#define MAXE    1024

// ---------------------------------------------------------------------------
// K1: h = X @ W  -> hbuf[N][C_DIM] row-major (fp32)
// C[m, c] = sum_f X[m,f] * W[c>>6][f][c&63]
// Tile 64x64, 256 threads, 4x4 per thread, K-step 16.
// Column tile (64) == one head => B slab is contiguous W[head][k0..k0+15][0..63].
// ---------------------------------------------------------------------------
__global__ __launch_bounds__(256) void gemm_h_kernel(
    const float* __restrict__ X, const float* __restrict__ W,
    float* __restrict__ hbuf) {
  __shared__ float As[16][68];
  __shared__ float Bs[16][68];
  const int m0   = blockIdx.x * 64;
  const int head = blockIdx.y;
  const float* Wh = W + (size_t)head * F_DIM * U_DIM;
  const int t  = threadIdx.x;
  const int tx = t & 15;        // col group (4 cols)
  const int ty = t >> 4;        // row group (4 rows)
  const int lm  = t >> 2;       // A-load row 0..63
  const int lk4 = (t & 3) * 4;  // A-load k offset
  const int bk  = t >> 4;       // B-load k row 0..15
  const int bc  = (t & 15) * 4; // B-load col offset

  float acc[4][4] = {};

  for (int k0 = 0; k0 < F_DIM; k0 += 16) {
    float4 av = *(const float4*)(X + (size_t)(m0 + lm) * F_DIM + k0 + lk4);
    As[lk4 + 0][lm] = av.x;
    As[lk4 + 1][lm] = av.y;
    As[lk4 + 2][lm] = av.z;
    As[lk4 + 3][lm] = av.w;
    float4 bv = *(const float4*)(Wh + (size_t)(k0 + bk) * U_DIM + bc);
    *(float4*)(&Bs[bk][bc]) = bv;
    __syncthreads();
#pragma unroll
    for (int kk = 0; kk < 16; ++kk) {
      float4 a4 = *(const float4*)(&As[kk][ty * 4]);
      float4 b4 = *(const float4*)(&Bs[kk][tx * 4]);
      float a[4] = {a4.x, a4.y, a4.z, a4.w};
      float b[4] = {b4.x, b4.y, b4.z, b4.w};
#pragma unroll
      for (int i = 0; i < 4; ++i)
#pragma unroll
        for (int j = 0; j < 4; ++j) acc[i][j] += a[i] * b[j];
    }
    __syncthreads();
  }
#pragma unroll
  for (int i = 0; i < 4; ++i) {
    int m = m0 + ty * 4 + i;
    float4 v = {acc[i][0], acc[i][1], acc[i][2], acc[i][3]};
    *(float4*)(hbuf + (size_t)m * C_DIM + head * U_DIM + tx * 4) = v;
  }
}

// ---------------------------------------------------------------------------
// K2: f_self[h,n] = h[h,n,:]·a_self[h,:], f_neigh likewise.
// One thread per (h, n).
// ---------------------------------------------------------------------------
__global__ __launch_bounds__(256) void logits_kernel(
    const float* __restrict__ hbuf, const float* __restrict__ a_self,
    const float* __restrict__ a_neigh, float* __restrict__ fs,
    float* __restrict__ fn) {
  int id = blockIdx.x * 256 + threadIdx.x;  // 0 .. H*N-1
  int n = id & (N_NODES - 1);
  int h = id >> 12;
  const float* hp  = hbuf + (size_t)n * C_DIM + h * U_DIM;
  const float* asp = a_self + h * U_DIM;
  const float* anp = a_neigh + h * U_DIM;
  float s = 0.f, m = 0.f;
#pragma unroll
  for (int u = 0; u < U_DIM; u += 4) {
    float4 hv = *(const float4*)(hp + u);
    float4 sv = *(const float4*)(asp + u);
    float4 nv = *(const float4*)(anp + u);
    s += hv.x * sv.x + hv.y * sv.y + hv.z * sv.z + hv.w * sv.w;
    m += hv.x * nv.x + hv.y * nv.y + hv.z * nv.z + hv.w * nv.w;
  }
  fs[id] = s;
  fn[id] = m;
}

// ---------------------------------------------------------------------------
// K3: per-node sparse attention + aggregation.
// Block = node i (256 threads). Deterministic edge-list compaction (prefix
// sum keeps sorted order), then per-head: lrelu logits -> max -> exp/sum ->
// weighted gather-aggregate of h, bias + relu, write out.
// ---------------------------------------------------------------------------
__global__ __launch_bounds__(256) void attn_agg_kernel(
    const float* __restrict__ A, const float* __restrict__ hbuf,
    const float* __restrict__ fs, const float* __restrict__ fn,
    const float* __restrict__ bias, float* __restrict__ out) {
  __shared__ int   eidx[MAXE];
  __shared__ float p[MAXE];
  __shared__ float red[256];
  __shared__ int   pref[256];

  const int i = blockIdx.x;
  const int t = threadIdx.x;
  const float* Arow = A + (size_t)i * N_NODES;

  // --- load my 16-element segment, count edges ---
  const int base = t * 16;
  float av[16];
#pragma unroll
  for (int q = 0; q < 4; ++q) {
    float4 x = *(const float4*)(Arow + base + q * 4);
    av[q * 4 + 0] = x.x;
    av[q * 4 + 1] = x.y;
    av[q * 4 + 2] = x.z;
    av[q * 4 + 3] = x.w;
  }
  int c = 0;
#pragma unroll
  for (int q = 0; q < 16; ++q) c += (av[q] != 0.0f) ? 1 : 0;

  // --- block inclusive prefix sum (Hillis-Steele) ---
  pref[t] = c;
  __syncthreads();
  for (int off = 1; off < 256; off <<= 1) {
    int val = (t >= off) ? pref[t - off] : 0;
    __syncthreads();
    pref[t] += val;
    __syncthreads();
  }
  int E = pref[255];
  if (E > MAXE) E = MAXE;  // statistically impossible, safety only
  int pos = pref[t] - c;
#pragma unroll
  for (int q = 0; q < 16; ++q) {
    if (av[q] != 0.0f) {
      if (pos < MAXE) eidx[pos] = base + q;
      ++pos;
    }
  }
  __syncthreads();

  const int u = t & 63;
  const int g = t >> 6;

  for (int h = 0; h < H_HEADS; ++h) {
    const float fsi = fs[h * N_NODES + i];
    const float* fnh = fn + h * N_NODES;
    // scores + local max
    float lmax = -1e30f;
    for (int e = t; e < E; e += 256) {
      float sc = fsi + fnh[eidx[e]];
      sc = (sc > 0.f) ? sc : LRELU_S * sc;
      p[e] = sc;
      lmax = fmaxf(lmax, sc);
    }
    red[t] = lmax;
    __syncthreads();
    for (int off = 128; off > 0; off >>= 1) {
      if (t < off) red[t] = fmaxf(red[t], red[t + off]);
      __syncthreads();
    }
    float m = red[0];
    __syncthreads();
    // exp + local sum
    float lsum = 0.f;
    for (int e = t; e < E; e += 256) {
      float pe = __expf(p[e] - m);
      p[e] = pe;
      lsum += pe;
    }
    red[t] = lsum;
    __syncthreads();
    for (int off = 128; off > 0; off >>= 1) {
      if (t < off) red[t] += red[t + off];
      __syncthreads();
    }
    float inv = 1.0f / red[0];
    __syncthreads();
    // aggregate: out[i, h*64+u] = (sum_e p[e] * h[eidx[e], h*64+u]) * inv
    float acc = 0.f;
    for (int e = g; e < E; e += 4) {
      acc += p[e] * hbuf[(size_t)eidx[e] * C_DIM + h * U_DIM + u];
    }
    red[t] = acc;
    __syncthreads();
    if (g == 0) {
      float tot = red[u] + red[64 + u] + red[128 + u] + red[192 + u];
      float val = tot * inv + bias[h * U_DIM + u];
      out[(size_t)i * C_DIM + h * U_DIM + u] = fmaxf(val, 0.f);
    }
    __syncthreads();
  }
}

// ---------------------------------------------------------------------------
extern "C" void kernel_launch(void* const* d_in, const int* in_sizes, int n_in,
                              void* d_out, int out_size, void* d_ws,
                              size_t ws_size, hipStream_t stream) {
  const float* X       = (const float*)d_in[0];
  // d_in[1] = out_indices (unused: final_layer=False returns all nodes)
  const float* A       = (const float*)d_in[2];
  const float* W       = (const float*)d_in[3];
  const float* a_self  = (const float*)d_in[4];
  const float* a_neigh = (const float*)d_in[5];
  const float* bias    = (const float*)d_in[6];
  float* out = (float*)d_out;

  float* hbuf = (float*)d_ws;                       // N * C_DIM
  float* fs   = hbuf + (size_t)N_NODES * C_DIM;     // H * N
  float* fn   = fs + (size_t)H_HEADS * N_NODES;     // H * N

  dim3 g1(N_NODES / 64, H_HEADS);
  gemm_h_kernel<<<g1, 256, 0, stream>>>(X, W, hbuf);

  logits_kernel<<<(H_HEADS * N_NODES) / 256, 256, 0, stream>>>(
      hbuf, a_self, a_neigh, fs, fn);

  attn_agg_kernel<<<N_NODES, 256, 0, stream>>>(A, hbuf, fs, fn, bias, out);
}

// Round 2
// 88.318 us; speedup vs baseline: 1.6847x; 1.6847x over previous
//
#include <hip/hip_runtime.h>
#include <hip/hip_bf16.h>

#define N_NODES 4096
#define F_DIM   512
#define U_DIM   64
#define H_HEADS 8
#define C_DIM   512   // H*U
#define LRELU_S 0.2f
#define MAXE    512   // >30 sigma above mean edge count (41 +/- 6.4)

// ---------------------------------------------------------------------------
// K1: h = X @ W  -> hbuf[N][C_DIM] row-major (fp32)
// ---------------------------------------------------------------------------
__global__ __launch_bounds__(256) void gemm_h_kernel(
    const float* __restrict__ X, const float* __restrict__ W,
    float* __restrict__ hbuf) {
  __shared__ float As[16][68];
  __shared__ float Bs[16][68];
  const int m0   = blockIdx.x * 64;
  const int head = blockIdx.y;
  const float* Wh = W + (size_t)head * F_DIM * U_DIM;
  const int t  = threadIdx.x;
  const int tx = t & 15;        // col group (4 cols)
  const int ty = t >> 4;        // row group (4 rows)
  const int lm  = t >> 2;       // A-load row 0..63
  const int lk4 = (t & 3) * 4;  // A-load k offset
  const int bk  = t >> 4;       // B-load k row 0..15
  const int bc  = (t & 15) * 4; // B-load col offset

  float acc[4][4] = {};

  for (int k0 = 0; k0 < F_DIM; k0 += 16) {
    float4 av = *(const float4*)(X + (size_t)(m0 + lm) * F_DIM + k0 + lk4);
    As[lk4 + 0][lm] = av.x;
    As[lk4 + 1][lm] = av.y;
    As[lk4 + 2][lm] = av.z;
    As[lk4 + 3][lm] = av.w;
    float4 bv = *(const float4*)(Wh + (size_t)(k0 + bk) * U_DIM + bc);
    *(float4*)(&Bs[bk][bc]) = bv;
    __syncthreads();
#pragma unroll
    for (int kk = 0; kk < 16; ++kk) {
      float4 a4 = *(const float4*)(&As[kk][ty * 4]);
      float4 b4 = *(const float4*)(&Bs[kk][tx * 4]);
      float a[4] = {a4.x, a4.y, a4.z, a4.w};
      float b[4] = {b4.x, b4.y, b4.z, b4.w};
#pragma unroll
      for (int i = 0; i < 4; ++i)
#pragma unroll
        for (int j = 0; j < 4; ++j) acc[i][j] += a[i] * b[j];
    }
    __syncthreads();
  }
#pragma unroll
  for (int i = 0; i < 4; ++i) {
    int m = m0 + ty * 4 + i;
    float4 v = {acc[i][0], acc[i][1], acc[i][2], acc[i][3]};
    *(float4*)(hbuf + (size_t)m * C_DIM + head * U_DIM + tx * 4) = v;
  }
}

// ---------------------------------------------------------------------------
// K2: f_self[h,n] = h[h,n,:]·a_self[h,:], f_neigh likewise.
// ---------------------------------------------------------------------------
__global__ __launch_bounds__(256) void logits_kernel(
    const float* __restrict__ hbuf, const float* __restrict__ a_self,
    const float* __restrict__ a_neigh, float* __restrict__ fs,
    float* __restrict__ fn) {
  int id = blockIdx.x * 256 + threadIdx.x;  // 0 .. H*N-1
  int n = id & (N_NODES - 1);
  int h = id >> 12;
  const float* hp  = hbuf + (size_t)n * C_DIM + h * U_DIM;
  const float* asp = a_self + h * U_DIM;
  const float* anp = a_neigh + h * U_DIM;
  float s = 0.f, m = 0.f;
#pragma unroll
  for (int u = 0; u < U_DIM; u += 4) {
    float4 hv = *(const float4*)(hp + u);
    float4 sv = *(const float4*)(asp + u);
    float4 nv = *(const float4*)(anp + u);
    s += hv.x * sv.x + hv.y * sv.y + hv.z * sv.z + hv.w * sv.w;
    m += hv.x * nv.x + hv.y * nv.y + hv.z * nv.z + hv.w * nv.w;
  }
  fs[id] = s;
  fn[id] = m;
}

// ---------------------------------------------------------------------------
// K3: per-node sparse attention + aggregation. 3 barriers per block total.
// Wave w owns heads {w, w+4} end-to-end (softmax AND aggregation), so the
// only cross-wave data is the compacted edge list.
// ---------------------------------------------------------------------------
__global__ __launch_bounds__(256) void attn_agg_kernel(
    const float* __restrict__ A, const float* __restrict__ hbuf,
    const float* __restrict__ fs, const float* __restrict__ fn,
    const float* __restrict__ bias, float* __restrict__ out) {
  __shared__ int   eidx[MAXE];
  __shared__ float p[H_HEADS][MAXE];   // 16 KB
  __shared__ int   wsum[4];

  const int i    = blockIdx.x;
  const int t    = threadIdx.x;
  const int lane = t & 63;
  const int w    = t >> 6;
  const float* Arow = A + (size_t)i * N_NODES;

  // --- load my 16-element segment of the A row, count edges ---
  const int base = t * 16;
  float av[16];
#pragma unroll
  for (int q = 0; q < 4; ++q) {
    float4 x = *(const float4*)(Arow + base + q * 4);
    av[q * 4 + 0] = x.x;
    av[q * 4 + 1] = x.y;
    av[q * 4 + 2] = x.z;
    av[q * 4 + 3] = x.w;
  }
  int c = 0;
#pragma unroll
  for (int q = 0; q < 16; ++q) c += (av[q] != 0.0f) ? 1 : 0;

  // --- wave-level inclusive prefix sum (shfl, no barriers) ---
  int psum = c;
#pragma unroll
  for (int off = 1; off < 64; off <<= 1) {
    int v = __shfl_up(psum, off);
    if (lane >= off) psum += v;
  }
  if (lane == 63) wsum[w] = psum;
  __syncthreads();  // barrier 1
  int woff = 0;
#pragma unroll
  for (int k = 0; k < 4; ++k)
    if (k < w) woff += wsum[k];
  int E = wsum[0] + wsum[1] + wsum[2] + wsum[3];
  if (E > MAXE) E = MAXE;  // statistically impossible, safety only

  int pos = woff + psum - c;  // exclusive prefix
#pragma unroll
  for (int q = 0; q < 16; ++q) {
    if (av[q] != 0.0f) {
      if (pos < MAXE) eidx[pos] = base + q;
      ++pos;
    }
  }
  __syncthreads();  // barrier 2: edge list ready

  // --- softmax: wave w handles heads w and w+4, lane-per-edge ---
#pragma unroll
  for (int hh = 0; hh < 2; ++hh) {
    const int h = w + hh * 4;
    const float fsi = fs[h * N_NODES + i];
    const float* fnh = fn + h * N_NODES;
    float lmax = -1e30f;
    for (int e = lane; e < E; e += 64) {
      float sc = fsi + fnh[eidx[e]];
      sc = (sc > 0.f) ? sc : LRELU_S * sc;
      p[h][e] = sc;
      lmax = fmaxf(lmax, sc);
    }
#pragma unroll
    for (int off = 32; off > 0; off >>= 1)
      lmax = fmaxf(lmax, __shfl_xor(lmax, off));
    float lsum = 0.f;
    for (int e = lane; e < E; e += 64) {
      float pe = __expf(p[h][e] - lmax);
      p[h][e] = pe;
      lsum += pe;
    }
#pragma unroll
    for (int off = 32; off > 0; off >>= 1) lsum += __shfl_xor(lsum, off);
    const float inv = 1.0f / lsum;
    for (int e = lane; e < E; e += 64) p[h][e] *= inv;
  }
  __syncthreads();  // barrier 3: p ready (eidx reuse across waves)

  // --- aggregation: wave w consumes heads w and w+4; lane = u; full serial
  //     edge sum per lane -> no cross-lane reduction needed ---
  const int h0 = w, h1 = w + 4;
  float acc0 = 0.f, acc1 = 0.f;
  for (int e = 0; e < E; ++e) {
    const int idx = eidx[e];
    const float* hb = hbuf + (size_t)idx * C_DIM;
    acc0 += p[h0][e] * hb[h0 * U_DIM + lane];
    acc1 += p[h1][e] * hb[h1 * U_DIM + lane];
  }
  float v0 = acc0 + bias[h0 * U_DIM + lane];
  float v1 = acc1 + bias[h1 * U_DIM + lane];
  out[(size_t)i * C_DIM + h0 * U_DIM + lane] = fmaxf(v0, 0.f);
  out[(size_t)i * C_DIM + h1 * U_DIM + lane] = fmaxf(v1, 0.f);
}

// ---------------------------------------------------------------------------
extern "C" void kernel_launch(void* const* d_in, const int* in_sizes, int n_in,
                              void* d_out, int out_size, void* d_ws,
                              size_t ws_size, hipStream_t stream) {
  const float* X       = (const float*)d_in[0];
  // d_in[1] = out_indices (unused: final_layer=False returns all nodes)
  const float* A       = (const float*)d_in[2];
  const float* W       = (const float*)d_in[3];
  const float* a_self  = (const float*)d_in[4];
  const float* a_neigh = (const float*)d_in[5];
  const float* bias    = (const float*)d_in[6];
  float* out = (float*)d_out;

  float* hbuf = (float*)d_ws;                       // N * C_DIM
  float* fs   = hbuf + (size_t)N_NODES * C_DIM;     // H * N
  float* fn   = fs + (size_t)H_HEADS * N_NODES;     // H * N

  dim3 g1(N_NODES / 64, H_HEADS);
  gemm_h_kernel<<<g1, 256, 0, stream>>>(X, W, hbuf);

  logits_kernel<<<(H_HEADS * N_NODES) / 256, 256, 0, stream>>>(
      hbuf, a_self, a_neigh, fs, fn);

  attn_agg_kernel<<<N_NODES, 256, 0, stream>>>(A, hbuf, fs, fn, bias, out);
}

// Round 3
// 59.163 us; speedup vs baseline: 2.5149x; 1.4928x over previous
//
#include <hip/hip_runtime.h>
#include <hip/hip_bf16.h>

#define N_NODES 4096
#define F_DIM   512
#define U_DIM   64
#define H_HEADS 8
#define C_DIM   512   // H*U
#define LRELU_S 0.2f
#define MAXE    512   // >30 sigma above mean edge count (41 +/- 6.4)

typedef __attribute__((ext_vector_type(8))) short bf16x8;
typedef __attribute__((ext_vector_type(4))) float f32x4;

__device__ inline unsigned short f2bf(float f) {
  union { float f; unsigned u; } v; v.f = f;
  unsigned r = v.u + 0x7FFFu + ((v.u >> 16) & 1u);  // round-to-nearest-even
  return (unsigned short)(r >> 16);
}
__device__ inline float bf2f(unsigned short b) {
  union { unsigned u; float f; } v; v.u = ((unsigned)b) << 16;
  return v.f;
}

// ---------------------------------------------------------------------------
// K1: h = X @ W -> hb[N][C_DIM] in BF16.
// MFMA bf16 16x16x32. Block tile 128(M) x 64(N=one head), 4 waves (2x2),
// each wave 64x32 (4x2 fragments). K-step 32. fp32->bf16 convert on stage.
// LDS padded +8 bf16 (stride 80 B) -> 2-way bank aliasing only (free).
// ---------------------------------------------------------------------------
__global__ __launch_bounds__(256) void gemm_h_kernel(
    const float* __restrict__ X, const float* __restrict__ W,
    unsigned short* __restrict__ hb) {
  __shared__ unsigned short As[128][40];  // As[m][k]
  __shared__ unsigned short Bs[64][40];   // Bs[u][k]  (B transposed)

  const int m0   = blockIdx.x * 128;
  const int head = blockIdx.y;            // n0 = head*64
  const float* Wh = W + (size_t)head * F_DIM * U_DIM;

  const int t    = threadIdx.x;
  const int lane = t & 63;
  const int w    = t >> 6;
  const int wr   = w >> 1;   // 0..1 : wave row (64 rows)
  const int wc   = w & 1;    // 0..1 : wave col (32 cols)

  const int arow  = t >> 1;        // A-stage row 0..127
  const int ahalf = (t & 1) * 16;  // A-stage k offset

  f32x4 acc[4][2] = {};

  for (int k0 = 0; k0 < F_DIM; k0 += 32) {
    // --- stage A: 128x32 fp32 -> bf16 ---
    {
      const float* src = X + (size_t)(m0 + arow) * F_DIM + k0 + ahalf;
      float4 f0 = ((const float4*)src)[0];
      float4 f1 = ((const float4*)src)[1];
      float4 f2 = ((const float4*)src)[2];
      float4 f3 = ((const float4*)src)[3];
      bf16x8 u0 = {(short)f2bf(f0.x), (short)f2bf(f0.y), (short)f2bf(f0.z),
                   (short)f2bf(f0.w), (short)f2bf(f1.x), (short)f2bf(f1.y),
                   (short)f2bf(f1.z), (short)f2bf(f1.w)};
      bf16x8 u1 = {(short)f2bf(f2.x), (short)f2bf(f2.y), (short)f2bf(f2.z),
                   (short)f2bf(f2.w), (short)f2bf(f3.x), (short)f2bf(f3.y),
                   (short)f2bf(f3.z), (short)f2bf(f3.w)};
      *(bf16x8*)&As[arow][ahalf]     = u0;
      *(bf16x8*)&As[arow][ahalf + 8] = u1;
    }
    // --- stage B (transposed): Bs[u][k] = W[head][k0+k][u] ---
    {
      const int kp = w * 8;
      const float* wsrc = Wh + (size_t)(k0 + kp) * U_DIM + lane;
      bf16x8 bv = {(short)f2bf(wsrc[0 * 64]), (short)f2bf(wsrc[1 * 64]),
                   (short)f2bf(wsrc[2 * 64]), (short)f2bf(wsrc[3 * 64]),
                   (short)f2bf(wsrc[4 * 64]), (short)f2bf(wsrc[5 * 64]),
                   (short)f2bf(wsrc[6 * 64]), (short)f2bf(wsrc[7 * 64])};
      *(bf16x8*)&Bs[lane][kp] = bv;
    }
    __syncthreads();

    // --- fragments + MFMA ---
    const int r  = lane & 15;
    const int ko = (lane >> 4) * 8;
    bf16x8 af[4], bfr[2];
#pragma unroll
    for (int mi = 0; mi < 4; ++mi)
      af[mi] = *(const bf16x8*)&As[wr * 64 + mi * 16 + r][ko];
#pragma unroll
    for (int ni = 0; ni < 2; ++ni)
      bfr[ni] = *(const bf16x8*)&Bs[wc * 32 + ni * 16 + r][ko];
#pragma unroll
    for (int mi = 0; mi < 4; ++mi)
#pragma unroll
      for (int ni = 0; ni < 2; ++ni)
        acc[mi][ni] = __builtin_amdgcn_mfma_f32_16x16x32_bf16(
            af[mi], bfr[ni], acc[mi][ni], 0, 0, 0);
    __syncthreads();
  }

  // --- C write: col=lane&15, row=(lane>>4)*4+reg (m89-verified mapping) ---
#pragma unroll
  for (int mi = 0; mi < 4; ++mi) {
#pragma unroll
    for (int ni = 0; ni < 2; ++ni) {
      const int row = m0 + wr * 64 + mi * 16 + (lane >> 4) * 4;
      const int col = head * 64 + wc * 32 + ni * 16 + (lane & 15);
#pragma unroll
      for (int reg = 0; reg < 4; ++reg)
        hb[(size_t)(row + reg) * C_DIM + col] = f2bf(acc[mi][ni][reg]);
    }
  }
}

// ---------------------------------------------------------------------------
// K2: f_self[h,n] = h[h,n,:]·a_self[h,:], f_neigh likewise. h in bf16.
// ---------------------------------------------------------------------------
__global__ __launch_bounds__(256) void logits_kernel(
    const unsigned short* __restrict__ hb, const float* __restrict__ a_self,
    const float* __restrict__ a_neigh, float* __restrict__ fs,
    float* __restrict__ fn) {
  int id = blockIdx.x * 256 + threadIdx.x;  // 0 .. H*N-1
  int n = id & (N_NODES - 1);
  int h = id >> 12;
  const unsigned short* hp = hb + (size_t)n * C_DIM + h * U_DIM;
  const float* asp = a_self + h * U_DIM;
  const float* anp = a_neigh + h * U_DIM;
  float s = 0.f, m = 0.f;
#pragma unroll
  for (int u = 0; u < U_DIM; u += 8) {
    bf16x8 hv = *(const bf16x8*)(hp + u);
#pragma unroll
    for (int j = 0; j < 8; ++j) {
      float hf = bf2f((unsigned short)hv[j]);
      s += hf * asp[u + j];
      m += hf * anp[u + j];
    }
  }
  fs[id] = s;
  fn[id] = m;
}

// ---------------------------------------------------------------------------
// K3: per-node sparse attention + aggregation. 3 barriers per block.
// Wave w owns heads {2w, 2w+1} end-to-end; h gathers are bf16 (4 MB total,
// per-XCD-L2 resident), two heads span one 256 B region per edge.
// ---------------------------------------------------------------------------
__global__ __launch_bounds__(256) void attn_agg_kernel(
    const float* __restrict__ A, const unsigned short* __restrict__ hb,
    const float* __restrict__ fs, const float* __restrict__ fn,
    const float* __restrict__ bias, float* __restrict__ out) {
  __shared__ int   eidx[MAXE];
  __shared__ float p[H_HEADS][MAXE];   // 16 KB
  __shared__ int   wsum[4];

  const int i    = blockIdx.x;
  const int t    = threadIdx.x;
  const int lane = t & 63;
  const int w    = t >> 6;
  const float* Arow = A + (size_t)i * N_NODES;

  // --- load my 16-element segment of the A row, count edges ---
  const int base = t * 16;
  float av[16];
#pragma unroll
  for (int q = 0; q < 4; ++q) {
    float4 x = *(const float4*)(Arow + base + q * 4);
    av[q * 4 + 0] = x.x;
    av[q * 4 + 1] = x.y;
    av[q * 4 + 2] = x.z;
    av[q * 4 + 3] = x.w;
  }
  int c = 0;
#pragma unroll
  for (int q = 0; q < 16; ++q) c += (av[q] != 0.0f) ? 1 : 0;

  // --- wave-level inclusive prefix sum (shfl, no barriers) ---
  int psum = c;
#pragma unroll
  for (int off = 1; off < 64; off <<= 1) {
    int v = __shfl_up(psum, off);
    if (lane >= off) psum += v;
  }
  if (lane == 63) wsum[w] = psum;
  __syncthreads();  // barrier 1
  int woff = 0;
#pragma unroll
  for (int k = 0; k < 4; ++k)
    if (k < w) woff += wsum[k];
  int E = wsum[0] + wsum[1] + wsum[2] + wsum[3];
  if (E > MAXE) E = MAXE;  // statistically impossible, safety only

  int pos = woff + psum - c;  // exclusive prefix
#pragma unroll
  for (int q = 0; q < 16; ++q) {
    if (av[q] != 0.0f) {
      if (pos < MAXE) eidx[pos] = base + q;
      ++pos;
    }
  }
  __syncthreads();  // barrier 2: edge list ready

  // --- softmax: wave w handles heads 2w, 2w+1, lane-per-edge ---
#pragma unroll
  for (int hh = 0; hh < 2; ++hh) {
    const int h = 2 * w + hh;
    const float fsi = fs[h * N_NODES + i];
    const float* fnh = fn + h * N_NODES;
    float lmax = -1e30f;
    for (int e = lane; e < E; e += 64) {
      float sc = fsi + fnh[eidx[e]];
      sc = (sc > 0.f) ? sc : LRELU_S * sc;
      p[h][e] = sc;
      lmax = fmaxf(lmax, sc);
    }
#pragma unroll
    for (int off = 32; off > 0; off >>= 1)
      lmax = fmaxf(lmax, __shfl_xor(lmax, off));
    float lsum = 0.f;
    for (int e = lane; e < E; e += 64) {
      float pe = __expf(p[h][e] - lmax);
      p[h][e] = pe;
      lsum += pe;
    }
#pragma unroll
    for (int off = 32; off > 0; off >>= 1) lsum += __shfl_xor(lsum, off);
    const float inv = 1.0f / lsum;
    for (int e = lane; e < E; e += 64) p[h][e] *= inv;
  }
  __syncthreads();  // barrier 3: p ready

  // --- aggregation: wave w consumes heads 2w, 2w+1; lane = u ---
  const int h0 = 2 * w, h1 = 2 * w + 1;
  float acc0 = 0.f, acc1 = 0.f;
  for (int e = 0; e < E; ++e) {
    const unsigned short* hp = hb + (size_t)eidx[e] * C_DIM;
    acc0 += p[h0][e] * bf2f(hp[h0 * U_DIM + lane]);
    acc1 += p[h1][e] * bf2f(hp[h1 * U_DIM + lane]);
  }
  float v0 = acc0 + bias[h0 * U_DIM + lane];
  float v1 = acc1 + bias[h1 * U_DIM + lane];
  out[(size_t)i * C_DIM + h0 * U_DIM + lane] = fmaxf(v0, 0.f);
  out[(size_t)i * C_DIM + h1 * U_DIM + lane] = fmaxf(v1, 0.f);
}

// ---------------------------------------------------------------------------
extern "C" void kernel_launch(void* const* d_in, const int* in_sizes, int n_in,
                              void* d_out, int out_size, void* d_ws,
                              size_t ws_size, hipStream_t stream) {
  const float* X       = (const float*)d_in[0];
  // d_in[1] = out_indices (unused: final_layer=False returns all nodes)
  const float* A       = (const float*)d_in[2];
  const float* W       = (const float*)d_in[3];
  const float* a_self  = (const float*)d_in[4];
  const float* a_neigh = (const float*)d_in[5];
  const float* bias    = (const float*)d_in[6];
  float* out = (float*)d_out;

  unsigned short* hb = (unsigned short*)d_ws;            // N*C bf16 (4 MB)
  float* fs = (float*)(hb + (size_t)N_NODES * C_DIM);    // H*N f32
  float* fn = fs + (size_t)H_HEADS * N_NODES;            // H*N f32

  dim3 g1(N_NODES / 128, H_HEADS);
  gemm_h_kernel<<<g1, 256, 0, stream>>>(X, W, hb);

  logits_kernel<<<(H_HEADS * N_NODES) / 256, 256, 0, stream>>>(
      hb, a_self, a_neigh, fs, fn);

  attn_agg_kernel<<<N_NODES, 256, 0, stream>>>(A, hb, fs, fn, bias, out);
}

// Round 4
// 46.217 us; speedup vs baseline: 3.2193x; 1.2801x over previous
//
#include <hip/hip_runtime.h>
#include <hip/hip_bf16.h>

#define N_NODES 4096
#define F_DIM   512
#define U_DIM   64
#define H_HEADS 8
#define C_DIM   512   // H*U
#define LRELU_S 0.2f
#define MAXE    128   // mean degree 42, sd 6.4; P(E>128) ~ 1e-25
#define GEMM_BLOCKS 512  // 64 m-blocks x 8 heads

typedef __attribute__((ext_vector_type(8))) short bf16x8;
typedef __attribute__((ext_vector_type(4))) float f32x4;

__device__ inline unsigned short f2bf(float f) {
  union { float f; unsigned u; } v; v.f = f;
  unsigned r = v.u + 0x7FFFu + ((v.u >> 16) & 1u);  // RTNE
  return (unsigned short)(r >> 16);
}
__device__ inline float bf2f(unsigned short b) {
  union { unsigned u; float f; } v; v.u = ((unsigned)b) << 16;
  return v.f;
}

// ---------------------------------------------------------------------------
// front_kernel: blocks [0, GEMM_BLOCKS) do h = X@W (bf16 MFMA, tile 64x64,
// 4 waves of 32x32) + fused f_self/f_neigh epilogue; blocks [GEMM_BLOCKS, ..)
// scan one A row each into CSR (deg, nbr). The HBM-bound scan overlaps the
// compute-bound GEMM within one dispatch.
// ---------------------------------------------------------------------------
__global__ __launch_bounds__(256) void front_kernel(
    const float* __restrict__ X, const float* __restrict__ W,
    const float* __restrict__ A, const float* __restrict__ a_self,
    const float* __restrict__ a_neigh, unsigned short* __restrict__ hb,
    float* __restrict__ fs, float* __restrict__ fn, int* __restrict__ deg,
    unsigned short* __restrict__ nbr) {
  __shared__ unsigned short As[64][72];  // +8 pad: 2-way bank alias only
  __shared__ unsigned short Bs[64][72];
  __shared__ int wsum[4];

  const int t    = threadIdx.x;
  const int lane = t & 63;
  const int w    = t >> 6;

  if ((int)blockIdx.x < GEMM_BLOCKS) {
    // ---------------- GEMM branch ----------------
    const int mblk = blockIdx.x & 63;
    const int head = blockIdx.x >> 6;
    const int m0   = mblk * 64;
    const float* Wh = W + (size_t)head * F_DIM * U_DIM;

    const int wr = w >> 1, wc = w & 1;   // wave grid 2x2, wave tile 32x32
    const int arow = t >> 2;             // A-stage row 0..63
    const int akc  = (t & 3) * 16;       // A-stage k offset
    const int bu   = t & 63;             // B-stage u
    const int bjc  = (t >> 6) * 16;      // B-stage k chunk

    f32x4 acc[2][2] = {};

    for (int k0 = 0; k0 < F_DIM; k0 += 64) {
      // stage A: 64x64 fp32 -> bf16, As[m][k]
      {
        const float* src = X + (size_t)(m0 + arow) * F_DIM + k0 + akc;
        float4 f0 = ((const float4*)src)[0];
        float4 f1 = ((const float4*)src)[1];
        float4 f2 = ((const float4*)src)[2];
        float4 f3 = ((const float4*)src)[3];
        bf16x8 u0 = {(short)f2bf(f0.x), (short)f2bf(f0.y), (short)f2bf(f0.z),
                     (short)f2bf(f0.w), (short)f2bf(f1.x), (short)f2bf(f1.y),
                     (short)f2bf(f1.z), (short)f2bf(f1.w)};
        bf16x8 u1 = {(short)f2bf(f2.x), (short)f2bf(f2.y), (short)f2bf(f2.z),
                     (short)f2bf(f2.w), (short)f2bf(f3.x), (short)f2bf(f3.y),
                     (short)f2bf(f3.z), (short)f2bf(f3.w)};
        *(bf16x8*)&As[arow][akc]     = u0;
        *(bf16x8*)&As[arow][akc + 8] = u1;
      }
      // stage B transposed: Bs[u][k] = W[head][k][u]
      {
        float bv[16];
#pragma unroll
        for (int j = 0; j < 16; ++j)
          bv[j] = Wh[(size_t)(k0 + bjc + j) * U_DIM + bu];
        bf16x8 w0 = {(short)f2bf(bv[0]), (short)f2bf(bv[1]), (short)f2bf(bv[2]),
                     (short)f2bf(bv[3]), (short)f2bf(bv[4]), (short)f2bf(bv[5]),
                     (short)f2bf(bv[6]), (short)f2bf(bv[7])};
        bf16x8 w1 = {(short)f2bf(bv[8]),  (short)f2bf(bv[9]),
                     (short)f2bf(bv[10]), (short)f2bf(bv[11]),
                     (short)f2bf(bv[12]), (short)f2bf(bv[13]),
                     (short)f2bf(bv[14]), (short)f2bf(bv[15])};
        *(bf16x8*)&Bs[bu][bjc]     = w0;
        *(bf16x8*)&Bs[bu][bjc + 8] = w1;
      }
      __syncthreads();

      const int r  = lane & 15;
      const int ko = (lane >> 4) * 8;
#pragma unroll
      for (int kk = 0; kk < 2; ++kk) {
        bf16x8 af0 = *(const bf16x8*)&As[wr * 32 + r][kk * 32 + ko];
        bf16x8 af1 = *(const bf16x8*)&As[wr * 32 + 16 + r][kk * 32 + ko];
        bf16x8 bf0 = *(const bf16x8*)&Bs[wc * 32 + r][kk * 32 + ko];
        bf16x8 bf1 = *(const bf16x8*)&Bs[wc * 32 + 16 + r][kk * 32 + ko];
        acc[0][0] = __builtin_amdgcn_mfma_f32_16x16x32_bf16(af0, bf0, acc[0][0], 0, 0, 0);
        acc[0][1] = __builtin_amdgcn_mfma_f32_16x16x32_bf16(af0, bf1, acc[0][1], 0, 0, 0);
        acc[1][0] = __builtin_amdgcn_mfma_f32_16x16x32_bf16(af1, bf0, acc[1][0], 0, 0, 0);
        acc[1][1] = __builtin_amdgcn_mfma_f32_16x16x32_bf16(af1, bf1, acc[1][1], 0, 0, 0);
      }
      __syncthreads();
    }

    // epilogue: write hb (global) + stash bf16 h-tile into As for logits
#pragma unroll
    for (int mi = 0; mi < 2; ++mi) {
#pragma unroll
      for (int ni = 0; ni < 2; ++ni) {
        const int rb = wr * 32 + mi * 16 + (lane >> 4) * 4;  // local row base
        const int cl = wc * 32 + ni * 16 + (lane & 15);      // local col
#pragma unroll
        for (int reg = 0; reg < 4; ++reg) {
          unsigned short hv = f2bf(acc[mi][ni][reg]);
          hb[(size_t)(m0 + rb + reg) * C_DIM + head * U_DIM + cl] = hv;
          As[rb + reg][cl] = hv;
        }
      }
    }
    __syncthreads();
    // fused logits: t<64 -> f_self row t; t in [64,128) -> f_neigh row t-64
    if (t < 128) {
      const int r = t & 63;
      const float* avec = (t >= 64) ? a_neigh + head * U_DIM
                                    : a_self + head * U_DIM;
      float s = 0.f;
#pragma unroll
      for (int u = 0; u < 64; ++u) s += bf2f(As[r][u]) * avec[u];
      float* dst = (t >= 64) ? fn : fs;
      dst[head * N_NODES + m0 + r] = s;
    }
  } else {
    // ---------------- scan branch: node i -> CSR ----------------
    const int i = (int)blockIdx.x - GEMM_BLOCKS;
    const float* Arow = A + (size_t)i * N_NODES;
    const int base = t * 16;
    float av[16];
#pragma unroll
    for (int q = 0; q < 4; ++q) {
      float4 x = *(const float4*)(Arow + base + q * 4);
      av[q * 4 + 0] = x.x;
      av[q * 4 + 1] = x.y;
      av[q * 4 + 2] = x.z;
      av[q * 4 + 3] = x.w;
    }
    int c = 0;
#pragma unroll
    for (int q = 0; q < 16; ++q) c += (av[q] != 0.0f) ? 1 : 0;

    int psum = c;
#pragma unroll
    for (int off = 1; off < 64; off <<= 1) {
      int v = __shfl_up(psum, off);
      if (lane >= off) psum += v;
    }
    if (lane == 63) wsum[w] = psum;
    __syncthreads();
    int woff = 0;
#pragma unroll
    for (int k = 0; k < 4; ++k)
      if (k < w) woff += wsum[k];
    int E = wsum[0] + wsum[1] + wsum[2] + wsum[3];
    if (E > MAXE) E = MAXE;  // P ~ 1e-25, safety only

    int pos = woff + psum - c;  // exclusive prefix
#pragma unroll
    for (int q = 0; q < 16; ++q) {
      if (av[q] != 0.0f) {
        if (pos < MAXE) nbr[(size_t)i * MAXE + pos] = (unsigned short)(base + q);
        ++pos;
      }
    }
    if (t == 0) deg[i] = E;
  }
}

// ---------------------------------------------------------------------------
// attn_kernel: per-node sparse softmax + aggregation from CSR.
// Wave w owns heads {2w, 2w+1}. Agg: lane l covers flat cols w*128+2l(+1);
// one dword gather per edge per lane serves both outputs.
// ---------------------------------------------------------------------------
__global__ __launch_bounds__(256) void attn_kernel(
    const unsigned short* __restrict__ hb, const float* __restrict__ fs,
    const float* __restrict__ fn, const float* __restrict__ bias,
    const int* __restrict__ deg, const unsigned short* __restrict__ nbr,
    float* __restrict__ out) {
  __shared__ int   eidx[MAXE];
  __shared__ float p[H_HEADS][MAXE];

  const int i    = blockIdx.x;
  const int t    = threadIdx.x;
  const int lane = t & 63;
  const int w    = t >> 6;
  const int E    = deg[i];

  if (t < E) eidx[t] = (int)nbr[(size_t)i * MAXE + t];
  __syncthreads();

  // softmax: wave w handles heads 2w, 2w+1 (E<=128 -> at most 2 lane-iters)
#pragma unroll
  for (int hh = 0; hh < 2; ++hh) {
    const int h = 2 * w + hh;
    const float fsi = fs[h * N_NODES + i];
    const float* fnh = fn + h * N_NODES;
    float lmax = -1e30f;
    for (int e = lane; e < E; e += 64) {
      float sc = fsi + fnh[eidx[e]];
      sc = (sc > 0.f) ? sc : LRELU_S * sc;
      p[h][e] = sc;
      lmax = fmaxf(lmax, sc);
    }
#pragma unroll
    for (int off = 32; off > 0; off >>= 1)
      lmax = fmaxf(lmax, __shfl_xor(lmax, off));
    float lsum = 0.f;
    for (int e = lane; e < E; e += 64) {
      float pe = __expf(p[h][e] - lmax);
      p[h][e] = pe;
      lsum += pe;
    }
#pragma unroll
    for (int off = 32; off > 0; off >>= 1) lsum += __shfl_xor(lsum, off);
    const float inv = 1.0f / lsum;
    for (int e = lane; e < E; e += 64) p[h][e] *= inv;
  }
  __syncthreads();

  // aggregation: lane l -> flat cols cbase, cbase+1 (same head h)
  const int cbase = w * 128 + 2 * lane;
  const int h = cbase >> 6;
  const float* ph = p[h];
  float acc0 = 0.f, acc1 = 0.f;
#pragma unroll 4
  for (int e = 0; e < E; ++e) {
    unsigned v = *(const unsigned*)(hb + (size_t)eidx[e] * C_DIM + cbase);
    float pe = ph[e];
    acc0 += pe * bf2f((unsigned short)(v & 0xFFFFu));
    acc1 += pe * bf2f((unsigned short)(v >> 16));
  }
  float2 bv = *(const float2*)(bias + cbase);
  out[(size_t)i * C_DIM + cbase]     = fmaxf(acc0 + bv.x, 0.f);
  out[(size_t)i * C_DIM + cbase + 1] = fmaxf(acc1 + bv.y, 0.f);
}

// ---------------------------------------------------------------------------
extern "C" void kernel_launch(void* const* d_in, const int* in_sizes, int n_in,
                              void* d_out, int out_size, void* d_ws,
                              size_t ws_size, hipStream_t stream) {
  const float* X       = (const float*)d_in[0];
  // d_in[1] = out_indices (unused: final_layer=False returns all nodes)
  const float* A       = (const float*)d_in[2];
  const float* W       = (const float*)d_in[3];
  const float* a_self  = (const float*)d_in[4];
  const float* a_neigh = (const float*)d_in[5];
  const float* bias    = (const float*)d_in[6];
  float* out = (float*)d_out;

  unsigned short* hb = (unsigned short*)d_ws;               // N*C bf16 (4 MB)
  float* fs = (float*)(hb + (size_t)N_NODES * C_DIM);       // H*N f32
  float* fn = fs + (size_t)H_HEADS * N_NODES;               // H*N f32
  int* deg  = (int*)(fn + (size_t)H_HEADS * N_NODES);       // N int
  unsigned short* nbr = (unsigned short*)(deg + N_NODES);   // N*MAXE ushort

  front_kernel<<<GEMM_BLOCKS + N_NODES, 256, 0, stream>>>(
      X, W, A, a_self, a_neigh, hb, fs, fn, deg, nbr);

  attn_kernel<<<N_NODES, 256, 0, stream>>>(hb, fs, fn, bias, deg, nbr, out);
}